// Round 7
// baseline (238.213 us; speedup 1.0000x reference)
//
#include <hip/hip_runtime.h>
#include <hip/hip_bf16.h>
#include <cstdint>
#include <cstddef>

typedef __attribute__((ext_vector_type(8))) short short8;
typedef __attribute__((ext_vector_type(4))) float f32x4;
typedef __attribute__((ext_vector_type(4))) int int4v;

__device__ __forceinline__ f32x4 mfma16x16x32(short8 a, short8 b, f32x4 c) {
    return __builtin_amdgcn_mfma_f32_16x16x32_bf16(a, b, c, 0, 0, 0);
}

__device__ __forceinline__ short f2bf(float f) {
    union { __hip_bfloat16 h; short s; } u;
    u.h = __float2bfloat16(f);
    return u.s;
}

__device__ __forceinline__ unsigned short f2bfu(float f) {
    union { __hip_bfloat16 h; unsigned short s; } u;
    u.h = __float2bfloat16(f);
    return u.s;
}

__device__ __forceinline__ float bf2f(unsigned short u) {
    union { float f; unsigned v; } x;
    x.v = ((unsigned)u) << 16;
    return x.f;
}

__device__ __forceinline__ short8 cvt8(f32x4 a, f32x4 b) {
    short8 r;
    r[0] = f2bf(a[0]); r[1] = f2bf(a[1]); r[2] = f2bf(a[2]); r[3] = f2bf(a[3]);
    r[4] = f2bf(b[0]); r[5] = f2bf(b[1]); r[6] = f2bf(b[2]); r[7] = f2bf(b[3]);
    return r;
}

// async global -> LDS, 16B per lane (LDS side = wave-uniform base + lane*16)
__device__ __forceinline__ void gload16(const void* g, void* l) {
    __builtin_amdgcn_global_load_lds(
        (__attribute__((address_space(1))) void*)g,
        (__attribute__((address_space(3))) void*)l,
        16, 0, 0);
}

// ---------------- fp32 -> bf16 weight conversion ----------------
struct Cvt4 { const float* s[4]; short* d[4]; };
__global__ __launch_bounds__(256)
void cvt_w4(Cvt4 a)
{
    const float* s = a.s[blockIdx.y];
    short* d = a.d[blockIdx.y];
    int i = (blockIdx.x * 256 + threadIdx.x) * 8;
    f32x4 x = *(const f32x4*)(s + i);
    f32x4 z = *(const f32x4*)(s + i + 4);
    *(short8*)(d + i) = cvt8(x, z);
}

// ======== Fused QKV projection, fp32-A direct staging ========
// grid (32, 8, 3), block 256. C[4096,1024] = A_fp32 @ W_bf16^T, BK=64.
// A-tile: 128x64 fp32 in LDS (32KB), swizzle pos=(col>>2)^(row&15).
// B-tile: 128x64 bf16 (16KB), swizzle chunk=(col>>3)^(row&7). Total 48KB -> 3/CU.
// z=0: Q split-head scaled 0.125; z=1: K split-head; z=2: V^T key-permuted.
struct QKV3 { const float* A[3]; const short* W[3]; short* dst[3]; };
__global__ __launch_bounds__(256, 3)
void gemm_qkv_f32a(QKV3 P)
{
    constexpr int K = 1024;
    __shared__ float lAf[128 * 64];
    __shared__ short lB[128 * 64];
    const int z = blockIdx.z;
    const float* __restrict__ A = P.A[z];
    const short* __restrict__ W = P.W[z];
    const int tid  = threadIdx.x;
    const int lane = tid & 63;
    const int wave = tid >> 6;
    const int quad = lane >> 4;
    const int l16  = lane & 15;
    const int wr   = wave >> 1;
    const int wc   = wave & 1;
    const int m0 = blockIdx.x * 128;
    const int n0 = blockIdx.y * 128;

    // A staging: wave covers rows wave*32..+32 in 8 slots of 4 rows.
    // lane i: row_sub = i>>4, swizzled position = i&15, global chunk = pos^(row&15)
    const int arow = lane >> 4;
    const int apos = lane & 15;
    const float* gA[8]; float* dA[8];
    #pragma unroll
    for (int s = 0; s < 8; s++) {
        int rb = wave * 32 + s * 4;
        int row = rb + arow;
        int cf = apos ^ (row & 15);
        gA[s] = A + (size_t)(m0 + row) * K + cf * 4;
        dA[s] = lAf + rb * 64;
    }
    // B staging: 4 slots of 8 rows (bf16). lane: row_sub = i>>3, chunk=(i&7)^((i>>3)&7)
    const int brow = lane >> 3;
    const int bch  = (lane & 7) ^ ((lane >> 3) & 7);
    const short* gB[4]; short* dB[4];
    #pragma unroll
    for (int t = 0; t < 4; t++) {
        int rb = wave * 32 + t * 8;
        gB[t] = W + (size_t)(n0 + rb + brow) * K + bch * 8;
        dB[t] = lB + rb * 64;
    }

    f32x4 acc[4][4] = {};

    for (int k0 = 0; k0 < K; k0 += 64) {
        __syncthreads();                 // prior reads done before overwrite
        #pragma unroll
        for (int s = 0; s < 8; s++) { gload16(gA[s], dA[s]); gA[s] += 64; }
        #pragma unroll
        for (int t = 0; t < 4; t++) { gload16(gB[t], dB[t]); gB[t] += 64; }
        __syncthreads();                 // vmcnt drained -> tiles ready
        #pragma unroll
        for (int h = 0; h < 2; h++) {
            short8 af[4], bfr[4];
            #pragma unroll
            for (int i = 0; i < 4; i++) {
                int row = wr * 64 + i * 16 + l16;
                int cf0 = h * 8 + quad * 2;
                f32x4 x = *(const f32x4*)(lAf + row * 64 + ((cf0 ^ (row & 15)) << 2));
                f32x4 y = *(const f32x4*)(lAf + row * 64 + (((cf0 + 1) ^ (row & 15)) << 2));
                af[i] = cvt8(x, y);
            }
            #pragma unroll
            for (int j = 0; j < 4; j++) {
                int row = wc * 64 + j * 16 + l16;
                bfr[j] = *(const short8*)(lB + row * 64 + (((h * 4 + quad) ^ (row & 7)) << 3));
            }
            #pragma unroll
            for (int i = 0; i < 4; i++)
                #pragma unroll
                for (int j = 0; j < 4; j++)
                    acc[i][j] = mfma16x16x32(af[i], bfr[j], acc[i][j]);
        }
    }

    short* dst = P.dst[z];
    const float scale = (z == 0) ? 0.125f : 1.0f;
    #pragma unroll
    for (int i = 0; i < 4; i++)
      #pragma unroll
      for (int j = 0; j < 4; j++)
        #pragma unroll
        for (int r = 0; r < 4; r++) {
            int gm = m0 + wr * 64 + i * 16 + quad * 4 + r;
            int gn = n0 + wc * 64 + j * 16 + l16;
            float val = acc[i][j][r] * scale;
            int bb = gm >> 11, s = gm & 2047, h = gn >> 6, d = gn & 63;
            if (z < 2) {
                dst[((size_t)(bb * 16 + h) * 2048 + s) * 64 + d] = f2bf(val);
            } else {
                int sp = (s & ~31) | (2 * (s & 15)) | ((s >> 4) & 1);
                dst[((size_t)(bb * 16 + h) * 64 + d) * 2048 + sp] = f2bf(val);
            }
        }
}

// Output projection: 64x128 tiles, grid (64, 8) = 512 blocks, BK=64, LDS 24KB.
__global__ __launch_bounds__(256, 3)
void gemm_out_lds(const short* __restrict__ A, const short* __restrict__ W,
                  float* __restrict__ dst)
{
    constexpr int K = 1024;
    __shared__ short lA[64 * 64];
    __shared__ short lB[128 * 64];
    const int tid  = threadIdx.x;
    const int lane = tid & 63;
    const int wave = tid >> 6;
    const int quad = lane >> 4;
    const int l16  = lane & 15;
    const int m0 = blockIdx.x * 64;
    const int n0 = blockIdx.y * 128;

    const int rsub = lane >> 3;
    const int gch  = (lane & 7) ^ ((lane >> 3) & 7);

    const short* gA[2]; const short* gB[4]; short* dA[2]; short* dB[4];
    #pragma unroll
    for (int t = 0; t < 2; t++) {
        int rb = wave * 16 + t * 8;
        gA[t] = A + (size_t)(m0 + rb + rsub) * K + gch * 8;
        dA[t] = lA + rb * 64;
    }
    #pragma unroll
    for (int t = 0; t < 4; t++) {
        int rb = wave * 32 + t * 8;
        gB[t] = W + (size_t)(n0 + rb + rsub) * K + gch * 8;
        dB[t] = lB + rb * 64;
    }
    const int skA = l16 & 7;

    f32x4 acc[4][2] = {};

    for (int k0 = 0; k0 < K; k0 += 64) {
        __syncthreads();
        #pragma unroll
        for (int t = 0; t < 2; t++) { gload16(gA[t], dA[t]); gA[t] += 64; }
        #pragma unroll
        for (int t = 0; t < 4; t++) { gload16(gB[t], dB[t]); gB[t] += 64; }
        __syncthreads();
        short8 af[4][2], bfr[2][2];
        #pragma unroll
        for (int i = 0; i < 4; i++)
            #pragma unroll
            for (int c = 0; c < 2; c++)
                af[i][c] = *(const short8*)(lA + (i * 16 + l16) * 64 +
                                            (((c * 4 + quad) ^ skA) << 3));
        #pragma unroll
        for (int j = 0; j < 2; j++)
            #pragma unroll
            for (int c = 0; c < 2; c++)
                bfr[j][c] = *(const short8*)(lB + (wave * 32 + j * 16 + l16) * 64 +
                                             (((c * 4 + quad) ^ skA) << 3));
        #pragma unroll
        for (int c = 0; c < 2; c++)
            #pragma unroll
            for (int i = 0; i < 4; i++)
                #pragma unroll
                for (int j = 0; j < 2; j++)
                    acc[i][j] = mfma16x16x32(af[i][c], bfr[j][c], acc[i][j]);
    }

    #pragma unroll
    for (int i = 0; i < 4; i++)
      #pragma unroll
      for (int j = 0; j < 2; j++)
        #pragma unroll
        for (int r = 0; r < 4; r++) {
            int gm = m0 + i * 16 + quad * 4 + r;
            int gn = n0 + wave * 32 + j * 16 + l16;
            dst[(size_t)gm * 1024 + gn] = acc[i][j][r];
        }
}

// ---------------- flash attention: 64 q-rows/block ----------------
// grid (32, 32), block 256 = 4 waves x 16 q-rows. 64-key tiles, double-buffered
// K/V LDS (32KB) + lP 8KB + bias 4KB = 44KB -> 3 blocks/CU.
__global__ __launch_bounds__(256, 3)
void flash_attn(const short* __restrict__ Qp, const short* __restrict__ Kp,
                const short* __restrict__ Vt, const int* __restrict__ mask,
                short* __restrict__ AO)
{
    __shared__ short lK[2][64 * 64];
    __shared__ short lV[2][64 * 64];
    __shared__ short lP[4][16 * 64];
    __shared__ unsigned short lbias[2048];   // bf16: 0x0000 or 0xFF80 (-inf)
    const int tid  = threadIdx.x;
    const int lane = tid & 63;
    const int wave = tid >> 6;
    const int quad = lane >> 4;
    const int l16  = lane & 15;
    const int bh = blockIdx.y;
    const int b  = bh >> 4;
    const int h  = bh & 15;
    const int q0 = blockIdx.x * 64 + wave * 16;

    {
        const int* mb = mask + b * 2048;
        for (int j = tid; j < 2048; j += 256)
            lbias[j] = mb[j] ? (unsigned short)0 : (unsigned short)0xFF80;
    }

    const short* Qb = Qp + (size_t)bh * 2048 * 64;
    const short* Kb = Kp + (size_t)bh * 2048 * 64;
    const short* Vb = Vt + (size_t)bh * 64 * 2048;

    short8 qf[2];
    #pragma unroll
    for (int c = 0; c < 2; c++)
        qf[c] = *(const short8*)(Qb + (q0 + l16) * 64 + c * 32 + quad * 8);

    const int c0 = tid, c1 = tid + 256;
    const int r0 = c0 >> 3, cc0 = c0 & 7;
    const int r1 = c1 >> 3, cc1 = c1 & 7;
    const int lo0 = r0 * 64 + ((cc0 ^ (r0 & 7)) << 3);
    const int lo1 = r1 * 64 + ((cc1 ^ (r1 & 7)) << 3);

    int4v kr0, kr1, vr0, vr1;
    auto prefetch = [&](int kt) {
        kr0 = *(const int4v*)(Kb + (size_t)(kt + r0) * 64 + cc0 * 8);
        kr1 = *(const int4v*)(Kb + (size_t)(kt + r1) * 64 + cc1 * 8);
        vr0 = *(const int4v*)(Vb + (size_t)r0 * 2048 + kt + cc0 * 8);
        vr1 = *(const int4v*)(Vb + (size_t)r1 * 2048 + kt + cc1 * 8);
    };
    auto stage = [&](int buf) {
        *(int4v*)(lK[buf] + lo0) = kr0;
        *(int4v*)(lK[buf] + lo1) = kr1;
        *(int4v*)(lV[buf] + lo0) = vr0;
        *(int4v*)(lV[buf] + lo1) = vr1;
    };

    prefetch(0);
    stage(0);
    __syncthreads();

    float lsum[4] = {};
    f32x4 o[4] = {};
    short* lp = lP[wave];

    for (int ti = 0; ti < 32; ti++) {
        const int cur = ti & 1;
        const int kt = ti * 64;
        if (ti < 31) prefetch(kt + 64);
        const short* K_ = lK[cur];
        const short* V_ = lV[cur];

        f32x4 s[4];
        #pragma unroll
        for (int kk = 0; kk < 4; kk++) {
            int row = kk * 16 + l16;
            short8 kf0 = *(const short8*)(K_ + row * 64 + ((quad ^ (row & 7)) << 3));
            short8 kf1 = *(const short8*)(K_ + row * 64 + (((4 + quad) ^ (row & 7)) << 3));
            f32x4 zv = {};
            zv = mfma16x16x32(qf[0], kf0, zv);
            zv = mfma16x16x32(qf[1], kf1, zv);
            s[kk] = zv;
        }

        float bias[4];
        #pragma unroll
        for (int kk = 0; kk < 4; kk++) bias[kk] = bf2f(lbias[kt + kk * 16 + l16]);

        #pragma unroll
        for (int g = 0; g < 2; g++)
            #pragma unroll
            for (int r = 0; r < 4; r++) {
                float p0 = __expf(s[2 * g][r]     + bias[2 * g]);
                float p1 = __expf(s[2 * g + 1][r] + bias[2 * g + 1]);
                lsum[r] += p0 + p1;
                unsigned pk = (unsigned)f2bfu(p0) | ((unsigned)f2bfu(p1) << 16);
                int row = quad * 4 + r;
                int ch  = 4 * g + (l16 >> 2);
                *(unsigned*)(lp + row * 64 + ((ch ^ (row & 7)) << 3) + ((2 * l16) & 7)) = pk;
            }
        __builtin_amdgcn_s_waitcnt(0xC07F);  // lgkmcnt(0): wave's LDS writes done

        short8 pf[2];
        #pragma unroll
        for (int c = 0; c < 2; c++)
            pf[c] = *(const short8*)(lp + l16 * 64 + (((c * 4 + quad) ^ (l16 & 7)) << 3));
        #pragma unroll
        for (int c = 0; c < 2; c++)
            #pragma unroll
            for (int dt = 0; dt < 4; dt++) {
                int row = dt * 16 + l16;
                short8 vf = *(const short8*)(V_ + row * 64 + (((c * 4 + quad) ^ (row & 7)) << 3));
                o[dt] = mfma16x16x32(pf[c], vf, o[dt]);
            }

        if (ti < 31) {
            stage(1 - cur);
            __syncthreads();
        }
    }

    #pragma unroll
    for (int off = 1; off < 16; off <<= 1)
        #pragma unroll
        for (int r = 0; r < 4; r++)
            lsum[r] += __shfl_xor(lsum[r], off);

    #pragma unroll
    for (int r = 0; r < 4; r++) {
        float inv = 1.0f / lsum[r];
        int sidx = q0 + quad * 4 + r;
        size_t base = ((size_t)(b * 2048 + sidx)) * 1024 + (size_t)h * 64;
        #pragma unroll
        for (int dt = 0; dt < 4; dt++)
            AO[base + dt * 16 + l16] = f2bf(o[dt][r] * inv);
    }
}

extern "C" void kernel_launch(void* const* d_in, const int* in_sizes, int n_in,
                              void* d_out, int out_size, void* d_ws, size_t ws_size,
                              hipStream_t stream)
{
    const float* q  = (const float*)d_in[0];
    const float* k  = (const float*)d_in[1];
    const float* v  = (const float*)d_in[2];
    const int* mask = (const int*)d_in[3];
    const float* wq = (const float*)d_in[4];
    const float* wk = (const float*)d_in[5];
    const float* wv = (const float*)d_in[6];
    const float* wo = (const float*)d_in[7];

    short* ws = (short*)d_ws;
    short* wqb = ws;                   // 1,048,576 shorts each
    short* wkb = ws + 1048576;
    short* wvb = ws + 2097152;
    short* wob = ws + 3145728;
    short* Qp  = ws + 4194304;         // [B,H,S,DK] bf16 (pre-scaled 1/8)
    short* Kp  = ws + 8388608;         // [B,H,S,DK]
    short* Vt  = ws + 12582912;        // [B,H,DK,S] key-permuted
    short* AO  = ws + 16777216;        // [B,S,D] merged heads
    // total 20,971,520 shorts = 40 MB (the proven-to-fit footprint)

    Cvt4 C;
    C.s[0] = wq; C.s[1] = wk; C.s[2] = wv; C.s[3] = wo;
    C.d[0] = wqb; C.d[1] = wkb; C.d[2] = wvb; C.d[3] = wob;
    hipLaunchKernelGGL(cvt_w4, dim3(512, 4), dim3(256), 0, stream, C);

    QKV3 P;
    P.A[0] = q;  P.A[1] = k;  P.A[2] = v;
    P.W[0] = wqb; P.W[1] = wkb; P.W[2] = wvb;
    P.dst[0] = Qp; P.dst[1] = Kp; P.dst[2] = Vt;
    hipLaunchKernelGGL(gemm_qkv_f32a, dim3(32, 8, 3), dim3(256), 0, stream, P);

    hipLaunchKernelGGL(flash_attn, dim3(32, 32), dim3(256), 0, stream,
                       Qp, Kp, Vt, mask, AO);

    hipLaunchKernelGGL(gemm_out_lds, dim3(64, 8), dim3(256), 0, stream,
                       AO, wob, (float*)d_out);
}

// Round 8
// 226.333 us; speedup vs baseline: 1.0525x; 1.0525x over previous
//
#include <hip/hip_runtime.h>
#include <hip/hip_bf16.h>
#include <cstdint>
#include <cstddef>

typedef __attribute__((ext_vector_type(8))) short short8;
typedef __attribute__((ext_vector_type(4))) float f32x4;
typedef __attribute__((ext_vector_type(4))) int int4v;

__device__ __forceinline__ f32x4 mfma16x16x32(short8 a, short8 b, f32x4 c) {
    return __builtin_amdgcn_mfma_f32_16x16x32_bf16(a, b, c, 0, 0, 0);
}

__device__ __forceinline__ short f2bf(float f) {
    union { __hip_bfloat16 h; short s; } u;
    u.h = __float2bfloat16(f);
    return u.s;
}

__device__ __forceinline__ unsigned short f2bfu(float f) {
    union { __hip_bfloat16 h; unsigned short s; } u;
    u.h = __float2bfloat16(f);
    return u.s;
}

__device__ __forceinline__ short8 cvt8(f32x4 a, f32x4 b) {
    short8 r;
    r[0] = f2bf(a[0]); r[1] = f2bf(a[1]); r[2] = f2bf(a[2]); r[3] = f2bf(a[3]);
    r[4] = f2bf(b[0]); r[5] = f2bf(b[1]); r[6] = f2bf(b[2]); r[7] = f2bf(b[3]);
    return r;
}

// async global -> LDS, 16B per lane (LDS side = wave-uniform base + lane*16)
__device__ __forceinline__ void gload16(const void* g, void* l) {
    __builtin_amdgcn_global_load_lds(
        (__attribute__((address_space(1))) void*)g,
        (__attribute__((address_space(3))) void*)l,
        16, 0, 0);
}

// ---------------- fp32 -> bf16 weight conversion ----------------
struct Cvt4 { const float* s[4]; short* d[4]; };
__global__ __launch_bounds__(256)
void cvt_w4(Cvt4 a)
{
    const float* s = a.s[blockIdx.y];
    short* d = a.d[blockIdx.y];
    int i = (blockIdx.x * 256 + threadIdx.x) * 8;
    f32x4 x = *(const f32x4*)(s + i);
    f32x4 z = *(const f32x4*)(s + i + 4);
    *(short8*)(d + i) = cvt8(x, z);
}

// ---------------- mask scan: cpos table + K-pad zeroing ----------------
// grid(2) = one block per batch. cpos[b*2048+s] = compacted index (or -1).
// Zeroes Kp rows [cnt, roundup64) for all 16 heads so the tail tile QK = 0.
__global__ __launch_bounds__(256)
void scan_mask(const int* __restrict__ mask, int* __restrict__ cpos,
               short* __restrict__ Kp)
{
    __shared__ int part[256];
    __shared__ int tot;
    const int b = blockIdx.x, tid = threadIdx.x;
    const int base = b * 2048;
    int loc[8], s0 = 0;
    #pragma unroll
    for (int j = 0; j < 8; j++) {
        loc[j] = (mask[base + tid * 8 + j] != 0) ? 1 : 0;
        s0 += loc[j];
    }
    part[tid] = s0;
    __syncthreads();
    if (tid == 0) {
        int acc = 0;
        for (int i = 0; i < 256; i++) { int t = part[i]; part[i] = acc; acc += t; }
        tot = acc;
    }
    __syncthreads();
    int c = part[tid];
    #pragma unroll
    for (int j = 0; j < 8; j++) {
        cpos[base + tid * 8 + j] = loc[j] ? c : -1;
        c += loc[j];
    }
    const int cnt = tot;
    const int pad = ((cnt + 63) & ~63) - cnt;
    for (int h = 0; h < 16; h++)
        for (int i = tid; i < pad * 64; i += 256) {
            int p = i >> 6, d = i & 63;
            Kp[(((size_t)(b * 16 + h)) * 2048 + cnt + p) * 64 + d] = 0;
        }
}

// ======== Fused QKV projection, fp32-A direct staging (r7 core) ========
// grid (32, 8, 3). z=0: Q split-head scaled 0.125; z=1: K compact-scattered;
// z=2: V^T compact-scattered + key-permuted.
struct QKV3 { const float* A[3]; const short* W[3]; short* dst[3]; const int* cp; };
__global__ __launch_bounds__(256, 3)
void gemm_qkv_f32a(QKV3 P)
{
    constexpr int K = 1024;
    __shared__ float lAf[128 * 64];
    __shared__ short lB[128 * 64];
    const int z = blockIdx.z;
    const float* __restrict__ A = P.A[z];
    const short* __restrict__ W = P.W[z];
    const int tid  = threadIdx.x;
    const int lane = tid & 63;
    const int wave = tid >> 6;
    const int quad = lane >> 4;
    const int l16  = lane & 15;
    const int wr   = wave >> 1;
    const int wc   = wave & 1;
    const int m0 = blockIdx.x * 128;
    const int n0 = blockIdx.y * 128;

    const int arow = lane >> 4;
    const int apos = lane & 15;
    const float* gA[8]; float* dA[8];
    #pragma unroll
    for (int s = 0; s < 8; s++) {
        int rb = wave * 32 + s * 4;
        int row = rb + arow;
        int cf = apos ^ (row & 15);
        gA[s] = A + (size_t)(m0 + row) * K + cf * 4;
        dA[s] = lAf + rb * 64;
    }
    const int brow = lane >> 3;
    const int bch  = (lane & 7) ^ ((lane >> 3) & 7);
    const short* gB[4]; short* dB[4];
    #pragma unroll
    for (int t = 0; t < 4; t++) {
        int rb = wave * 32 + t * 8;
        gB[t] = W + (size_t)(n0 + rb + brow) * K + bch * 8;
        dB[t] = lB + rb * 64;
    }

    f32x4 acc[4][4] = {};

    for (int k0 = 0; k0 < K; k0 += 64) {
        __syncthreads();
        #pragma unroll
        for (int s = 0; s < 8; s++) { gload16(gA[s], dA[s]); gA[s] += 64; }
        #pragma unroll
        for (int t = 0; t < 4; t++) { gload16(gB[t], dB[t]); gB[t] += 64; }
        __syncthreads();
        #pragma unroll
        for (int h = 0; h < 2; h++) {
            short8 af[4], bfr[4];
            #pragma unroll
            for (int i = 0; i < 4; i++) {
                int row = wr * 64 + i * 16 + l16;
                int cf0 = h * 8 + quad * 2;
                f32x4 x = *(const f32x4*)(lAf + row * 64 + ((cf0 ^ (row & 15)) << 2));
                f32x4 y = *(const f32x4*)(lAf + row * 64 + (((cf0 + 1) ^ (row & 15)) << 2));
                af[i] = cvt8(x, y);
            }
            #pragma unroll
            for (int j = 0; j < 4; j++) {
                int row = wc * 64 + j * 16 + l16;
                bfr[j] = *(const short8*)(lB + row * 64 + (((h * 4 + quad) ^ (row & 7)) << 3));
            }
            #pragma unroll
            for (int i = 0; i < 4; i++)
                #pragma unroll
                for (int j = 0; j < 4; j++)
                    acc[i][j] = mfma16x16x32(af[i], bfr[j], acc[i][j]);
        }
    }

    short* dst = P.dst[z];
    const int* cp = P.cp;
    const float scale = (z == 0) ? 0.125f : 1.0f;
    #pragma unroll
    for (int i = 0; i < 4; i++)
      #pragma unroll
      for (int j = 0; j < 4; j++)
        #pragma unroll
        for (int r = 0; r < 4; r++) {
            int gm = m0 + wr * 64 + i * 16 + quad * 4 + r;
            int gn = n0 + wc * 64 + j * 16 + l16;
            float val = acc[i][j][r] * scale;
            int bb = gm >> 11, s = gm & 2047, h = gn >> 6, d = gn & 63;
            if (z == 0) {
                dst[((size_t)(bb * 16 + h) * 2048 + s) * 64 + d] = f2bf(val);
            } else if (z == 1) {
                int c = cp[bb * 2048 + s];
                if (c >= 0)
                    dst[((size_t)(bb * 16 + h) * 2048 + c) * 64 + d] = f2bf(val);
            } else {
                int c = cp[bb * 2048 + s];
                if (c >= 0) {
                    int sp = (c & ~31) | (2 * (c & 15)) | ((c >> 4) & 1);
                    dst[((size_t)(bb * 16 + h) * 64 + d) * 2048 + sp] = f2bf(val);
                }
            }
        }
}

// Output projection: 64x128 tiles, grid (64, 8) = 512 blocks, BK=64 (r7, unchanged)
__global__ __launch_bounds__(256, 3)
void gemm_out_lds(const short* __restrict__ A, const short* __restrict__ W,
                  float* __restrict__ dst)
{
    constexpr int K = 1024;
    __shared__ short lA[64 * 64];
    __shared__ short lB[128 * 64];
    const int tid  = threadIdx.x;
    const int lane = tid & 63;
    const int wave = tid >> 6;
    const int quad = lane >> 4;
    const int l16  = lane & 15;
    const int m0 = blockIdx.x * 64;
    const int n0 = blockIdx.y * 128;

    const int rsub = lane >> 3;
    const int gch  = (lane & 7) ^ ((lane >> 3) & 7);

    const short* gA[2]; const short* gB[4]; short* dA[2]; short* dB[4];
    #pragma unroll
    for (int t = 0; t < 2; t++) {
        int rb = wave * 16 + t * 8;
        gA[t] = A + (size_t)(m0 + rb + rsub) * K + gch * 8;
        dA[t] = lA + rb * 64;
    }
    #pragma unroll
    for (int t = 0; t < 4; t++) {
        int rb = wave * 32 + t * 8;
        gB[t] = W + (size_t)(n0 + rb + rsub) * K + gch * 8;
        dB[t] = lB + rb * 64;
    }
    const int skA = l16 & 7;

    f32x4 acc[4][2] = {};

    for (int k0 = 0; k0 < K; k0 += 64) {
        __syncthreads();
        #pragma unroll
        for (int t = 0; t < 2; t++) { gload16(gA[t], dA[t]); gA[t] += 64; }
        #pragma unroll
        for (int t = 0; t < 4; t++) { gload16(gB[t], dB[t]); gB[t] += 64; }
        __syncthreads();
        short8 af[4][2], bfr[2][2];
        #pragma unroll
        for (int i = 0; i < 4; i++)
            #pragma unroll
            for (int c = 0; c < 2; c++)
                af[i][c] = *(const short8*)(lA + (i * 16 + l16) * 64 +
                                            (((c * 4 + quad) ^ skA) << 3));
        #pragma unroll
        for (int j = 0; j < 2; j++)
            #pragma unroll
            for (int c = 0; c < 2; c++)
                bfr[j][c] = *(const short8*)(lB + (wave * 32 + j * 16 + l16) * 64 +
                                             (((c * 4 + quad) ^ skA) << 3));
        #pragma unroll
        for (int c = 0; c < 2; c++)
            #pragma unroll
            for (int i = 0; i < 4; i++)
                #pragma unroll
                for (int j = 0; j < 2; j++)
                    acc[i][j] = mfma16x16x32(af[i][c], bfr[j][c], acc[i][j]);
    }

    #pragma unroll
    for (int i = 0; i < 4; i++)
      #pragma unroll
      for (int j = 0; j < 2; j++)
        #pragma unroll
        for (int r = 0; r < 4; r++) {
            int gm = m0 + i * 16 + quad * 4 + r;
            int gn = n0 + wave * 32 + j * 16 + l16;
            dst[(size_t)gm * 1024 + gn] = acc[i][j][r];
        }
}

// ---------------- flash attention: 128 q-rows/block + compacted keys ----------------
// grid (16, 32), block 256 = 4 waves x 32 q-rows. Keys pre-compacted to cnt
// unmasked positions; loop ceil(cnt/64) tiles; bias = pos<cnt ? 0 : -inf.
__global__ __launch_bounds__(256, 3)
void flash_attn(const short* __restrict__ Qp, const short* __restrict__ Kp,
                const short* __restrict__ Vt, const int* __restrict__ mask,
                short* __restrict__ AO)
{
    __shared__ short lK[2][64 * 64];
    __shared__ short lV[2][64 * 64];
    __shared__ short lP[8][16 * 64];
    __shared__ int red[256];
    const int tid  = threadIdx.x;
    const int lane = tid & 63;
    const int wave = tid >> 6;
    const int quad = lane >> 4;
    const int l16  = lane & 15;
    const int bh = blockIdx.y;
    const int b  = bh >> 4;
    const int h  = bh & 15;
    const int q0 = blockIdx.x * 128 + wave * 32;

    // count unmasked keys in-block (no cross-kernel workspace hazard)
    {
        int s0 = 0;
        for (int j = tid; j < 2048; j += 256) s0 += (mask[b * 2048 + j] != 0) ? 1 : 0;
        red[tid] = s0;
        __syncthreads();
        if (tid < 128) red[tid] += red[tid + 128]; __syncthreads();
        if (tid < 64)  red[tid] += red[tid + 64];  __syncthreads();
        if (tid < 32)  red[tid] += red[tid + 32];  __syncthreads();
        if (tid < 16)  red[tid] += red[tid + 16];  __syncthreads();
        if (tid < 8)   red[tid] += red[tid + 8];   __syncthreads();
        if (tid < 4)   red[tid] += red[tid + 4];   __syncthreads();
        if (tid < 2)   red[tid] += red[tid + 2];   __syncthreads();
        if (tid < 1)   red[tid] += red[tid + 1];   __syncthreads();
    }
    const int cnt = red[0];
    const int nt  = (cnt + 63) >> 6;

    const short* Qb = Qp + (size_t)bh * 2048 * 64;
    const short* Kb = Kp + (size_t)bh * 2048 * 64;
    const short* Vb = Vt + (size_t)bh * 64 * 2048;

    short8 qf[2][2];
    #pragma unroll
    for (int t = 0; t < 2; t++)
        #pragma unroll
        for (int c = 0; c < 2; c++)
            qf[t][c] = *(const short8*)(Qb + (q0 + t * 16 + l16) * 64 + c * 32 + quad * 8);

    const int c0 = tid, c1 = tid + 256;
    const int r0 = c0 >> 3, cc0 = c0 & 7;
    const int r1 = c1 >> 3, cc1 = c1 & 7;
    const int lo0 = r0 * 64 + ((cc0 ^ (r0 & 7)) << 3);
    const int lo1 = r1 * 64 + ((cc1 ^ (r1 & 7)) << 3);

    int4v kr0, kr1, vr0, vr1;
    auto prefetch = [&](int kt) {
        kr0 = *(const int4v*)(Kb + (size_t)(kt + r0) * 64 + cc0 * 8);
        kr1 = *(const int4v*)(Kb + (size_t)(kt + r1) * 64 + cc1 * 8);
        vr0 = *(const int4v*)(Vb + (size_t)r0 * 2048 + kt + cc0 * 8);
        vr1 = *(const int4v*)(Vb + (size_t)r1 * 2048 + kt + cc1 * 8);
    };
    auto stage = [&](int buf) {
        *(int4v*)(lK[buf] + lo0) = kr0;
        *(int4v*)(lK[buf] + lo1) = kr1;
        *(int4v*)(lV[buf] + lo0) = vr0;
        *(int4v*)(lV[buf] + lo1) = vr1;
    };

    prefetch(0);
    stage(0);
    __syncthreads();

    float lsum[2][4] = {};
    f32x4 o[2][4] = {};
    short* lp[2] = { lP[wave * 2], lP[wave * 2 + 1] };

    for (int ti = 0; ti < nt; ti++) {
        const int cur = ti & 1;
        const int kt = ti * 64;
        if (ti < nt - 1) prefetch(kt + 64);
        const short* K_ = lK[cur];
        const short* V_ = lV[cur];

        f32x4 s[2][4];
        #pragma unroll
        for (int kk = 0; kk < 4; kk++) {
            int row = kk * 16 + l16;
            short8 kf0 = *(const short8*)(K_ + row * 64 + ((quad ^ (row & 7)) << 3));
            short8 kf1 = *(const short8*)(K_ + row * 64 + (((4 + quad) ^ (row & 7)) << 3));
            #pragma unroll
            for (int t = 0; t < 2; t++) {
                f32x4 z = {};
                z = mfma16x16x32(qf[t][0], kf0, z);
                z = mfma16x16x32(qf[t][1], kf1, z);
                s[t][kk] = z;
            }
        }

        float bias[4];
        #pragma unroll
        for (int kk = 0; kk < 4; kk++)
            bias[kk] = (kt + kk * 16 + l16 < cnt) ? 0.f : -__builtin_inff();

        #pragma unroll
        for (int t = 0; t < 2; t++)
            #pragma unroll
            for (int g = 0; g < 2; g++)
                #pragma unroll
                for (int r = 0; r < 4; r++) {
                    float p0 = __expf(s[t][2 * g][r]     + bias[2 * g]);
                    float p1 = __expf(s[t][2 * g + 1][r] + bias[2 * g + 1]);
                    lsum[t][r] += p0 + p1;
                    unsigned pk = (unsigned)f2bfu(p0) | ((unsigned)f2bfu(p1) << 16);
                    int row = quad * 4 + r;
                    int ch  = 4 * g + (l16 >> 2);
                    *(unsigned*)(lp[t] + row * 64 + ((ch ^ (row & 7)) << 3) + ((2 * l16) & 7)) = pk;
                }
        __builtin_amdgcn_s_waitcnt(0xC07F);  // lgkmcnt(0): wave's LDS writes done

        short8 pf[2][2];
        #pragma unroll
        for (int t = 0; t < 2; t++)
            #pragma unroll
            for (int c = 0; c < 2; c++)
                pf[t][c] = *(const short8*)(lp[t] + l16 * 64 + (((c * 4 + quad) ^ (l16 & 7)) << 3));
        #pragma unroll
        for (int c = 0; c < 2; c++)
            #pragma unroll
            for (int dt = 0; dt < 4; dt++) {
                int row = dt * 16 + l16;
                short8 vf = *(const short8*)(V_ + row * 64 + (((c * 4 + quad) ^ (row & 7)) << 3));
                o[0][dt] = mfma16x16x32(pf[0][c], vf, o[0][dt]);
                o[1][dt] = mfma16x16x32(pf[1][c], vf, o[1][dt]);
            }

        if (ti < nt - 1) {
            stage(1 - cur);
            __syncthreads();
        }
    }

    #pragma unroll
    for (int off = 1; off < 16; off <<= 1)
        #pragma unroll
        for (int t = 0; t < 2; t++)
            #pragma unroll
            for (int r = 0; r < 4; r++)
                lsum[t][r] += __shfl_xor(lsum[t][r], off);

    #pragma unroll
    for (int t = 0; t < 2; t++)
        #pragma unroll
        for (int r = 0; r < 4; r++) {
            float inv = 1.0f / fmaxf(lsum[t][r], 1e-30f);
            int sidx = q0 + t * 16 + quad * 4 + r;
            size_t base = ((size_t)(b * 2048 + sidx)) * 1024 + (size_t)h * 64;
            #pragma unroll
            for (int dt = 0; dt < 4; dt++)
                AO[base + dt * 16 + l16] = f2bf(o[t][dt][r] * inv);
        }
}

extern "C" void kernel_launch(void* const* d_in, const int* in_sizes, int n_in,
                              void* d_out, int out_size, void* d_ws, size_t ws_size,
                              hipStream_t stream)
{
    const float* q  = (const float*)d_in[0];
    const float* k  = (const float*)d_in[1];
    const float* v  = (const float*)d_in[2];
    const int* mask = (const int*)d_in[3];
    const float* wq = (const float*)d_in[4];
    const float* wk = (const float*)d_in[5];
    const float* wv = (const float*)d_in[6];
    const float* wo = (const float*)d_in[7];

    short* ws = (short*)d_ws;
    short* wqb = ws;                   // 1,048,576 shorts each
    short* wkb = ws + 1048576;
    short* wvb = ws + 2097152;
    short* wob = ws + 3145728;
    short* Qp  = ws + 4194304;         // [B,H,S,DK] bf16 (pre-scaled 1/8)
    short* Kp  = ws + 8388608;         // [B,H,S,DK] compacted keys + zero pad
    short* Vt  = ws + 12582912;        // [B,H,DK,S] compacted + key-permuted
    short* AO  = ws + 16777216;        // [B,S,D] merged heads (flash -> out)
    int* cpos  = (int*)AO;             // 16KB alias; lifetime scan -> qkv only

    Cvt4 C;
    C.s[0] = wq; C.s[1] = wk; C.s[2] = wv; C.s[3] = wo;
    C.d[0] = wqb; C.d[1] = wkb; C.d[2] = wvb; C.d[3] = wob;
    hipLaunchKernelGGL(cvt_w4, dim3(512, 4), dim3(256), 0, stream, C);

    hipLaunchKernelGGL(scan_mask, dim3(2), dim3(256), 0, stream, mask, cpos, Kp);

    QKV3 P;
    P.A[0] = q;  P.A[1] = k;  P.A[2] = v;
    P.W[0] = wqb; P.W[1] = wkb; P.W[2] = wvb;
    P.dst[0] = Qp; P.dst[1] = Kp; P.dst[2] = Vt;
    P.cp = cpos;
    hipLaunchKernelGGL(gemm_qkv_f32a, dim3(32, 8, 3), dim3(256), 0, stream, P);

    hipLaunchKernelGGL(flash_attn, dim3(16, 32), dim3(256), 0, stream,
                       Qp, Kp, Vt, mask, AO);

    hipLaunchKernelGGL(gemm_out_lds, dim3(64, 8), dim3(256), 0, stream,
                       AO, wob, (float*)d_out);
}